// Round 4
// baseline (259.119 us; speedup 1.0000x reference)
//
#include <hip/hip_runtime.h>
#include <math.h>

// ---------------------------------------------------------------------------
// GCN 2-layer via gather. Two CSR strategies, chosen by ws_size (fixed per
// session, so the choice is stable across graph replays):
//   PADDED (preferred): one atomic pass builds a level-major padded CSR
//     slots[p*n + d] = src  (p = ticket from atomicAdd on deg[d], p < S=48)
//     -> no scan, no fill pass, gather reads are wave-coalesced.
//   EXACT (fallback, proven R3 path): count+rank atomics, 3-kernel scan,
//     atomic-free fill into dense CSR.
// g[j] = dinv[j]*(x[j]@W);  out[i] = dinv[i]*(sum_{j->i} g[j] + g[i]) + b
// ---------------------------------------------------------------------------

#define SLOTS 48  // P(in-degree >= 48) ~ 1e-11 per node at E=1.6M, n=1e5

// ======================== PADDED path ========================

__global__ void k_build_padded(const int* __restrict__ src, const int* __restrict__ dst,
                               int* __restrict__ deg, int* __restrict__ slots,
                               int n, int E) {
    int e = blockIdx.x * blockDim.x + threadIdx.x;
    if (e >= E) return;
    int d = dst[e];
    int p = atomicAdd(&deg[d], 1);
    if (p < SLOTS) slots[(size_t)p * n + d] = src[e];
}

__global__ void k_dinv(const int* __restrict__ deg, float* __restrict__ dinv, int n) {
    int i = blockIdx.x * blockDim.x + threadIdx.x;
    if (i < n) dinv[i] = rsqrtf((float)(deg[i] + 1));  // +1 = self-loop
}

// Fused: gather layer-1 + relu/bias + (z @ W2) -> g2 padded to float4.
// 4 threads per node, thread c4 owns features [4*c4, 4*c4+4).
// Level-major slots: wave's 16 nodes read 64 contiguous bytes per k.
__global__ void k_gather1_p(const float4* __restrict__ g1v, const int* __restrict__ slots,
                            const int* __restrict__ deg, const float* __restrict__ dinv,
                            const float* __restrict__ b1, const float* __restrict__ W2,
                            float4* __restrict__ g2p, int n) {
    int idx = blockIdx.x * 256 + threadIdx.x;
    int i = idx >> 2, c4 = idx & 3;
    if (i >= n) return;
    int dg = min(deg[i], SLOTS);
    float4 acc = g1v[(size_t)i * 4 + c4];  // self-loop term
    for (int k = 0; k < dg; ++k) {
        int s = slots[(size_t)k * n + i];
        float4 v = g1v[(size_t)s * 4 + c4];
        acc.x += v.x; acc.y += v.y; acc.z += v.z; acc.w += v.w;
    }
    float di = dinv[i];
    float z0 = fmaxf(0.f, di * acc.x + b1[c4 * 4 + 0]);
    float z1 = fmaxf(0.f, di * acc.y + b1[c4 * 4 + 1]);
    float z2 = fmaxf(0.f, di * acc.z + b1[c4 * 4 + 2]);
    float z3 = fmaxf(0.f, di * acc.w + b1[c4 * 4 + 3]);
    const float* w = W2 + c4 * 12;  // rows 4*c4 .. 4*c4+3 of [16][3]
    float o0 = z0 * w[0] + z1 * w[3] + z2 * w[6] + z3 * w[9];
    float o1 = z0 * w[1] + z1 * w[4] + z2 * w[7] + z3 * w[10];
    float o2 = z0 * w[2] + z1 * w[5] + z2 * w[8] + z3 * w[11];
    o0 += __shfl_xor(o0, 1); o0 += __shfl_xor(o0, 2);
    o1 += __shfl_xor(o1, 1); o1 += __shfl_xor(o1, 2);
    o2 += __shfl_xor(o2, 1); o2 += __shfl_xor(o2, 2);
    if (c4 == 0) g2p[i] = make_float4(di * o0, di * o1, di * o2, 0.f);
}

// Fused: gather layer-2 + bias + log_softmax. 4 threads/node split k-levels.
__global__ void k_gather2_p(const float4* __restrict__ g2p, const int* __restrict__ slots,
                            const int* __restrict__ deg, const float* __restrict__ dinv,
                            const float* __restrict__ b2, float* __restrict__ out, int n) {
    int idx = blockIdx.x * 256 + threadIdx.x;
    int i = idx >> 2, t = idx & 3;
    if (i >= n) return;
    int dg = min(deg[i], SLOTS);
    float v0 = 0.f, v1 = 0.f, v2 = 0.f;
    for (int k = t; k < dg; k += 4) {
        int s = slots[(size_t)k * n + i];
        float4 g = g2p[s];
        v0 += g.x; v1 += g.y; v2 += g.z;
    }
    v0 += __shfl_xor(v0, 1); v0 += __shfl_xor(v0, 2);
    v1 += __shfl_xor(v1, 1); v1 += __shfl_xor(v1, 2);
    v2 += __shfl_xor(v2, 1); v2 += __shfl_xor(v2, 2);
    if (t != 0) return;
    float4 self = g2p[i];
    float di = dinv[i];
    float a0 = di * (v0 + self.x) + b2[0];
    float a1 = di * (v1 + self.y) + b2[1];
    float a2 = di * (v2 + self.z) + b2[2];
    float m = fmaxf(a0, fmaxf(a1, a2));
    float e0 = expf(a0 - m), e1 = expf(a1 - m), e2 = expf(a2 - m);
    float lse = logf(e0 + e1 + e2);
    out[(size_t)i * 3 + 0] = a0 - m - lse;
    out[(size_t)i * 3 + 1] = a1 - m - lse;
    out[(size_t)i * 3 + 2] = a2 - m - lse;
}

// ======================== shared GEMM1 ========================

// g1[row][c] = dinv[row] * sum_k x[row][k] * W1[k][c];  4 threads per row
__global__ void k_gemm1(const float* __restrict__ x, const float* __restrict__ W1,
                        const float* __restrict__ dinv, float4* __restrict__ g1v, int n) {
    __shared__ float4 sW4[512];  // W1 [128][16] as [k][c4] float4
    int tid = threadIdx.x;
    for (int i = tid; i < 512; i += 256) sW4[i] = ((const float4*)W1)[i];
    __syncthreads();
    int idx = blockIdx.x * 256 + tid;
    int row = idx >> 2, c4 = idx & 3;
    if (row >= n) return;
    const float4* xr = (const float4*)(x + (size_t)row * 128);
    float4 acc = make_float4(0.f, 0.f, 0.f, 0.f);
    for (int q = 0; q < 32; ++q) {
        float4 xv = xr[q];
        #pragma unroll
        for (int j = 0; j < 4; ++j) {
            float s = (j == 0) ? xv.x : (j == 1) ? xv.y : (j == 2) ? xv.z : xv.w;
            float4 w = sW4[(q * 4 + j) * 4 + c4];
            acc.x += s * w.x; acc.y += s * w.y; acc.z += s * w.z; acc.w += s * w.w;
        }
    }
    float di = dinv[row];
    acc.x *= di; acc.y *= di; acc.z *= di; acc.w *= di;
    g1v[(size_t)row * 4 + c4] = acc;
}

// ======================== EXACT fallback path (R3) ========================

__global__ void k_count_rank(const int* __restrict__ dst, int* __restrict__ deg,
                             unsigned short* __restrict__ rank, int E) {
    int e = blockIdx.x * blockDim.x + threadIdx.x;
    if (e >= E) return;
    int d = dst[e];
    int p = atomicAdd(&deg[d], 1);
    rank[e] = (unsigned short)p;
}

__global__ void k_scan_block(const int* __restrict__ deg, int* __restrict__ bsum, int n) {
    __shared__ int s[256];
    int t = threadIdx.x;
    int i = blockIdx.x * 256 + t;
    s[t] = (i < n) ? deg[i] : 0;
    __syncthreads();
    for (int o = 128; o > 0; o >>= 1) {
        if (t < o) s[t] += s[t + o];
        __syncthreads();
    }
    if (t == 0) bsum[blockIdx.x] = s[0];
}

__global__ void k_scan_top(int* __restrict__ bsum, int nb) {
    __shared__ int s[512];
    int t = threadIdx.x;
    int orig = (t < nb) ? bsum[t] : 0;
    s[t] = orig;
    __syncthreads();
    for (int o = 1; o < 512; o <<= 1) {
        int add = (t >= o) ? s[t - o] : 0;
        __syncthreads();
        s[t] += add;
        __syncthreads();
    }
    if (t < nb) bsum[t] = s[t] - orig;
}

__global__ void k_row_start(const int* __restrict__ deg, const int* __restrict__ bsum,
                            int* __restrict__ row_start, float* __restrict__ dinv, int n) {
    __shared__ int s[256];
    int t = threadIdx.x;
    int i = blockIdx.x * 256 + t;
    int v = (i < n) ? deg[i] : 0;
    s[t] = v;
    __syncthreads();
    for (int o = 1; o < 256; o <<= 1) {
        int add = (t >= o) ? s[t - o] : 0;
        __syncthreads();
        s[t] += add;
        __syncthreads();
    }
    if (i < n) {
        row_start[i] = bsum[blockIdx.x] + s[t] - v;
        dinv[i] = rsqrtf((float)(v + 1));
    }
}

__global__ void k_fill(const int* __restrict__ src, const int* __restrict__ dst,
                       const int* __restrict__ row_start, const unsigned short* __restrict__ rank,
                       int* __restrict__ csr, int E) {
    int e = blockIdx.x * blockDim.x + threadIdx.x;
    if (e >= E) return;
    csr[row_start[dst[e]] + (int)rank[e]] = src[e];
}

__global__ void k_gather1_e(const float4* __restrict__ g1v, const int* __restrict__ csr,
                            const int* __restrict__ row_start, const int* __restrict__ deg,
                            const float* __restrict__ dinv, const float* __restrict__ b1,
                            const float* __restrict__ W2, float4* __restrict__ g2p, int n) {
    int idx = blockIdx.x * 256 + threadIdx.x;
    int i = idx >> 2, c4 = idx & 3;
    if (i >= n) return;
    int off = row_start[i], dg = deg[i];
    float4 acc = g1v[(size_t)i * 4 + c4];
    for (int k = 0; k < dg; ++k) {
        int s = csr[off + k];
        float4 v = g1v[(size_t)s * 4 + c4];
        acc.x += v.x; acc.y += v.y; acc.z += v.z; acc.w += v.w;
    }
    float di = dinv[i];
    float z0 = fmaxf(0.f, di * acc.x + b1[c4 * 4 + 0]);
    float z1 = fmaxf(0.f, di * acc.y + b1[c4 * 4 + 1]);
    float z2 = fmaxf(0.f, di * acc.z + b1[c4 * 4 + 2]);
    float z3 = fmaxf(0.f, di * acc.w + b1[c4 * 4 + 3]);
    const float* w = W2 + c4 * 12;
    float o0 = z0 * w[0] + z1 * w[3] + z2 * w[6] + z3 * w[9];
    float o1 = z0 * w[1] + z1 * w[4] + z2 * w[7] + z3 * w[10];
    float o2 = z0 * w[2] + z1 * w[5] + z2 * w[8] + z3 * w[11];
    o0 += __shfl_xor(o0, 1); o0 += __shfl_xor(o0, 2);
    o1 += __shfl_xor(o1, 1); o1 += __shfl_xor(o1, 2);
    o2 += __shfl_xor(o2, 1); o2 += __shfl_xor(o2, 2);
    if (c4 == 0) g2p[i] = make_float4(di * o0, di * o1, di * o2, 0.f);
}

__global__ void k_gather2_e(const float4* __restrict__ g2p, const int* __restrict__ csr,
                            const int* __restrict__ row_start, const int* __restrict__ deg,
                            const float* __restrict__ dinv, const float* __restrict__ b2,
                            float* __restrict__ out, int n) {
    int idx = blockIdx.x * 256 + threadIdx.x;
    int i = idx >> 2, t = idx & 3;
    if (i >= n) return;
    int off = row_start[i], dg = deg[i];
    float v0 = 0.f, v1 = 0.f, v2 = 0.f;
    for (int k = t; k < dg; k += 4) {
        int s = csr[off + k];
        float4 g = g2p[s];
        v0 += g.x; v1 += g.y; v2 += g.z;
    }
    v0 += __shfl_xor(v0, 1); v0 += __shfl_xor(v0, 2);
    v1 += __shfl_xor(v1, 1); v1 += __shfl_xor(v1, 2);
    v2 += __shfl_xor(v2, 1); v2 += __shfl_xor(v2, 2);
    if (t != 0) return;
    float4 self = g2p[i];
    float di = dinv[i];
    float a0 = di * (v0 + self.x) + b2[0];
    float a1 = di * (v1 + self.y) + b2[1];
    float a2 = di * (v2 + self.z) + b2[2];
    float m = fmaxf(a0, fmaxf(a1, a2));
    float e0 = expf(a0 - m), e1 = expf(a1 - m), e2 = expf(a2 - m);
    float lse = logf(e0 + e1 + e2);
    out[(size_t)i * 3 + 0] = a0 - m - lse;
    out[(size_t)i * 3 + 1] = a1 - m - lse;
    out[(size_t)i * 3 + 2] = a2 - m - lse;
}

// ======================== launch ========================

extern "C" void kernel_launch(void* const* d_in, const int* in_sizes, int n_in,
                              void* d_out, int out_size, void* d_ws, size_t ws_size,
                              hipStream_t stream) {
    const float* x  = (const float*)d_in[0];
    const int*   ei = (const int*)d_in[1];
    const float* W1 = (const float*)d_in[2];
    const float* b1 = (const float*)d_in[3];
    const float* W2 = (const float*)d_in[4];
    const float* b2 = (const float*)d_in[5];
    float* out = (float*)d_out;

    const int n = in_sizes[0] / 128;   // 100000
    const int E = in_sizes[1] / 2;     // 1600000
    const int* src = ei;
    const int* dst = ei + E;

    const int B = 256;
    int gn  = (n + B - 1) / B;
    int gn4 = (4 * n + B - 1) / B;
    int gE  = (E + B - 1) / B;

    size_t need_padded = (size_t)(22 + SLOTS) * n * 4;  // 28 MB at n=1e5

    if (ws_size >= need_padded) {
        // ---- PADDED path ----
        char* ws = (char*)d_ws;
        int*   deg   = (int*)ws;                            // n
        float* dinv  = (float*)(ws + (size_t)n * 4);        // n
        float* g1    = (float*)(ws + (size_t)2 * n * 4);    // 16n
        float* g2p   = g1 + (size_t)16 * n;                 // 4n
        int*   slots = (int*)(ws + (size_t)22 * n * 4);     // SLOTS*n

        hipMemsetAsync(deg, 0, (size_t)n * sizeof(int), stream);
        k_build_padded<<<gE, B, 0, stream>>>(src, dst, deg, slots, n, E);
        k_dinv<<<gn, B, 0, stream>>>(deg, dinv, n);
        k_gemm1<<<gn4, B, 0, stream>>>(x, W1, dinv, (float4*)g1, n);
        k_gather1_p<<<gn4, B, 0, stream>>>((const float4*)g1, slots, deg, dinv, b1, W2,
                                           (float4*)g2p, n);
        k_gather2_p<<<gn4, B, 0, stream>>>((const float4*)g2p, slots, deg, dinv, b2, out, n);
    } else {
        // ---- EXACT fallback (R3) ----
        char* ws = (char*)d_ws;
        int*   deg       = (int*)ws;
        float* dinv      = (float*)(ws + (size_t)n * 4);
        int*   row_start = (int*)(ws + (size_t)2 * n * 4);
        int*   bsum      = (int*)(ws + (size_t)3 * n * 4);
        int*   csr       = (int*)(ws + (size_t)3 * n * 4 + 2048);
        float* g1        = (float*)(ws + (size_t)3 * n * 4 + 2048 + (size_t)E * 4);
        float* g2p       = g1 + (size_t)16 * n;
        unsigned short* rank = (unsigned short*)g1;  // dead before g1 is written

        hipMemsetAsync(deg, 0, (size_t)n * sizeof(int), stream);
        k_count_rank<<<gE, B, 0, stream>>>(dst, deg, rank, E);
        k_scan_block<<<gn, B, 0, stream>>>(deg, bsum, n);
        k_scan_top<<<1, 512, 0, stream>>>(bsum, gn);
        k_row_start<<<gn, B, 0, stream>>>(deg, bsum, row_start, dinv, n);
        k_fill<<<gE, B, 0, stream>>>(src, dst, row_start, rank, csr, E);
        k_gemm1<<<gn4, B, 0, stream>>>(x, W1, dinv, (float4*)g1, n);
        k_gather1_e<<<gn4, B, 0, stream>>>((const float4*)g1, csr, row_start, deg, dinv, b1, W2,
                                           (float4*)g2p, n);
        k_gather2_e<<<gn4, B, 0, stream>>>((const float4*)g2p, csr, row_start, deg, dinv, b2,
                                           out, n);
    }
}

// Round 5
// 233.965 us; speedup vs baseline: 1.1075x; 1.1075x over previous
//
#include <hip/hip_runtime.h>
#include <math.h>

// ---------------------------------------------------------------------------
// GCN 2-layer via exact dst-ordered CSR + gather (R3 structure) with
// fat-kernel co-scheduling: the latency-bound atomic passes are overlapped
// with independent BW/VALU work by interleaving block populations.
//   FAT1: [h = x@W1 (unscaled)]  ||  [deg ticket atomics + rank]
//   scan (3 kernels) -> row_start, dinv
//   FAT2: [csr fill (atomic-free via rank)]  ||  [g1 *= dinv]
//   gather1 (+relu/bias+W2), gather2 (+bias+log_softmax)
// ---------------------------------------------------------------------------

// ======================== FAT1: gemm1 || count_rank ========================
__global__ void k_fat1(const float* __restrict__ x, const float* __restrict__ W1,
                       float4* __restrict__ g1v,
                       const int* __restrict__ dst, int* __restrict__ deg,
                       unsigned short* __restrict__ rank, int n, int E) {
    __shared__ float4 sW4[512];  // W1 [128][16] as [k][c4] float4 (gemm half only)
    int b = blockIdx.x;
    if ((b & 1) == 0) {
        // ---- gemm section: h[row][c] = sum_k x[row][k]*W1[k][c] (NO dinv yet)
        int tid = threadIdx.x;
        for (int i = tid; i < 512; i += 256) sW4[i] = ((const float4*)W1)[i];
        __syncthreads();
        int idx = (b >> 1) * 256 + tid;
        int row = idx >> 2, c4 = idx & 3;
        if (row >= n) return;
        const float4* xr = (const float4*)(x + (size_t)row * 128);
        float4 acc = make_float4(0.f, 0.f, 0.f, 0.f);
        for (int q = 0; q < 32; ++q) {
            float4 xv = xr[q];
            #pragma unroll
            for (int j = 0; j < 4; ++j) {
                float s = (j == 0) ? xv.x : (j == 1) ? xv.y : (j == 2) ? xv.z : xv.w;
                float4 w = sW4[(q * 4 + j) * 4 + c4];
                acc.x += s * w.x; acc.y += s * w.y; acc.z += s * w.z; acc.w += s * w.w;
            }
        }
        g1v[(size_t)row * 4 + c4] = acc;
    } else {
        // ---- count+rank section: grid-stride over edges (multiple in flight)
        int T = (gridDim.x >> 1) * 256;
        int tid = (b >> 1) * 256 + threadIdx.x;
        for (int e = tid; e < E; e += T) {
            int d = dst[e];
            int p = atomicAdd(&deg[d], 1);
            rank[e] = (unsigned short)p;
        }
    }
}

// ======================== scan: deg -> row_start, dinv ========================
__global__ void k_scan_block(const int* __restrict__ deg, int* __restrict__ bsum, int n) {
    __shared__ int s[256];
    int t = threadIdx.x;
    int i = blockIdx.x * 256 + t;
    s[t] = (i < n) ? deg[i] : 0;
    __syncthreads();
    for (int o = 128; o > 0; o >>= 1) {
        if (t < o) s[t] += s[t + o];
        __syncthreads();
    }
    if (t == 0) bsum[blockIdx.x] = s[0];
}

__global__ void k_scan_top(int* __restrict__ bsum, int nb) {  // 1 block, 512 thr
    __shared__ int s[512];
    int t = threadIdx.x;
    int orig = (t < nb) ? bsum[t] : 0;
    s[t] = orig;
    __syncthreads();
    for (int o = 1; o < 512; o <<= 1) {
        int add = (t >= o) ? s[t - o] : 0;
        __syncthreads();
        s[t] += add;
        __syncthreads();
    }
    if (t < nb) bsum[t] = s[t] - orig;  // exclusive
}

__global__ void k_row_start(const int* __restrict__ deg, const int* __restrict__ bsum,
                            int* __restrict__ row_start, float* __restrict__ dinv, int n) {
    __shared__ int s[256];
    int t = threadIdx.x;
    int i = blockIdx.x * 256 + t;
    int v = (i < n) ? deg[i] : 0;
    s[t] = v;
    __syncthreads();
    for (int o = 1; o < 256; o <<= 1) {
        int add = (t >= o) ? s[t - o] : 0;
        __syncthreads();
        s[t] += add;
        __syncthreads();
    }
    if (i < n) {
        row_start[i] = bsum[blockIdx.x] + s[t] - v;  // exclusive
        dinv[i] = rsqrtf((float)(v + 1));            // +1 = self-loop
    }
}

// ======================== FAT2: fill || scale g1 ========================
__global__ void k_fat2(const int* __restrict__ src, const int* __restrict__ dst,
                       const int* __restrict__ row_start,
                       const unsigned short* __restrict__ rank, int* __restrict__ csr,
                       const float* __restrict__ dinv, float4* __restrict__ g1v,
                       int n, int E) {
    int b = blockIdx.x;
    if ((b & 1) == 0) {
        // ---- atomic-free CSR fill
        int T = (gridDim.x >> 1) * 256;
        int tid = (b >> 1) * 256 + threadIdx.x;
        for (int e = tid; e < E; e += T) {
            csr[row_start[dst[e]] + (int)rank[e]] = src[e];
        }
    } else {
        // ---- g1 *= dinv (one float4 per thread; 4 threads share a row)
        int idx = (b >> 1) * 256 + threadIdx.x;
        int row = idx >> 2;
        if (row >= n) return;
        float di = dinv[row];
        float4 v = g1v[idx];
        v.x *= di; v.y *= di; v.z *= di; v.w *= di;
        g1v[idx] = v;
    }
}

// ======================== gathers (R3, unchanged) ========================
// Fused: gather layer-1 + relu/bias + (z @ W2) -> g2 padded to float4.
__global__ void k_gather1(const float4* __restrict__ g1v, const int* __restrict__ csr,
                          const int* __restrict__ row_start, const int* __restrict__ deg,
                          const float* __restrict__ dinv, const float* __restrict__ b1,
                          const float* __restrict__ W2, float4* __restrict__ g2p, int n) {
    int idx = blockIdx.x * 256 + threadIdx.x;
    int i = idx >> 2, c4 = idx & 3;
    if (i >= n) return;
    int off = row_start[i], dg = deg[i];
    float4 acc = g1v[(size_t)i * 4 + c4];  // self-loop term
    for (int k = 0; k < dg; ++k) {
        int s = csr[off + k];
        float4 v = g1v[(size_t)s * 4 + c4];
        acc.x += v.x; acc.y += v.y; acc.z += v.z; acc.w += v.w;
    }
    float di = dinv[i];
    float z0 = fmaxf(0.f, di * acc.x + b1[c4 * 4 + 0]);
    float z1 = fmaxf(0.f, di * acc.y + b1[c4 * 4 + 1]);
    float z2 = fmaxf(0.f, di * acc.z + b1[c4 * 4 + 2]);
    float z3 = fmaxf(0.f, di * acc.w + b1[c4 * 4 + 3]);
    const float* w = W2 + c4 * 12;  // rows 4*c4 .. 4*c4+3 of [16][3]
    float o0 = z0 * w[0] + z1 * w[3] + z2 * w[6] + z3 * w[9];
    float o1 = z0 * w[1] + z1 * w[4] + z2 * w[7] + z3 * w[10];
    float o2 = z0 * w[2] + z1 * w[5] + z2 * w[8] + z3 * w[11];
    o0 += __shfl_xor(o0, 1); o0 += __shfl_xor(o0, 2);
    o1 += __shfl_xor(o1, 1); o1 += __shfl_xor(o1, 2);
    o2 += __shfl_xor(o2, 1); o2 += __shfl_xor(o2, 2);
    if (c4 == 0) g2p[i] = make_float4(di * o0, di * o1, di * o2, 0.f);
}

// Fused: gather layer-2 + bias + log_softmax. 4 threads/node split edges.
__global__ void k_gather2(const float4* __restrict__ g2p, const int* __restrict__ csr,
                          const int* __restrict__ row_start, const int* __restrict__ deg,
                          const float* __restrict__ dinv, const float* __restrict__ b2,
                          float* __restrict__ out, int n) {
    int idx = blockIdx.x * 256 + threadIdx.x;
    int i = idx >> 2, t = idx & 3;
    if (i >= n) return;
    int off = row_start[i], dg = deg[i];
    float v0 = 0.f, v1 = 0.f, v2 = 0.f;
    for (int k = t; k < dg; k += 4) {
        int s = csr[off + k];
        float4 g = g2p[s];
        v0 += g.x; v1 += g.y; v2 += g.z;
    }
    v0 += __shfl_xor(v0, 1); v0 += __shfl_xor(v0, 2);
    v1 += __shfl_xor(v1, 1); v1 += __shfl_xor(v1, 2);
    v2 += __shfl_xor(v2, 1); v2 += __shfl_xor(v2, 2);
    if (t != 0) return;
    float4 self = g2p[i];
    float di = dinv[i];
    float a0 = di * (v0 + self.x) + b2[0];
    float a1 = di * (v1 + self.y) + b2[1];
    float a2 = di * (v2 + self.z) + b2[2];
    float m = fmaxf(a0, fmaxf(a1, a2));
    float e0 = expf(a0 - m), e1 = expf(a1 - m), e2 = expf(a2 - m);
    float lse = logf(e0 + e1 + e2);
    out[(size_t)i * 3 + 0] = a0 - m - lse;
    out[(size_t)i * 3 + 1] = a1 - m - lse;
    out[(size_t)i * 3 + 2] = a2 - m - lse;
}

// ======================== launch ========================
extern "C" void kernel_launch(void* const* d_in, const int* in_sizes, int n_in,
                              void* d_out, int out_size, void* d_ws, size_t ws_size,
                              hipStream_t stream) {
    const float* x  = (const float*)d_in[0];
    const int*   ei = (const int*)d_in[1];      // [2][E]
    const float* W1 = (const float*)d_in[2];    // [128][16]
    const float* b1 = (const float*)d_in[3];    // [16]
    const float* W2 = (const float*)d_in[4];    // [16][3]
    const float* b2 = (const float*)d_in[5];    // [3]
    float* out = (float*)d_out;

    const int n = in_sizes[0] / 128;   // 100000
    const int E = in_sizes[1] / 2;     // 1600000
    const int* src = ei;
    const int* dst = ei + E;

    // workspace layout (bytes; all offsets 16B-aligned for these sizes)
    char* ws = (char*)d_ws;
    int*   deg       = (int*)ws;                                   // n ints (memset 0)
    float* dinv      = (float*)(ws + (size_t)4 * n);               // n floats
    int*   row_start = (int*)(ws + (size_t)8 * n);                 // n ints
    int*   bsum      = (int*)(ws + (size_t)12 * n);                // 512 ints
    int*   csr       = (int*)(ws + (size_t)12 * n + 2048);         // E ints
    unsigned short* rank = (unsigned short*)(ws + (size_t)12 * n + 2048 + (size_t)4 * E); // E u16
    float* g1        = (float*)(ws + (size_t)12 * n + 2048 + (size_t)6 * E);  // 16n floats
    float* g2p       = g1 + (size_t)16 * n;                        // 4n floats

    hipMemsetAsync(deg, 0, (size_t)n * sizeof(int), stream);

    const int B = 256;
    int gn  = (n + B - 1) / B;          // node-grid / #scan blocks (<= 512)
    int gn4 = (4 * n + B - 1) / B;      // 4-threads-per-node grid

    k_fat1<<<2 * gn4, B, 0, stream>>>(x, W1, (float4*)g1, dst, deg, rank, n, E);
    k_scan_block<<<gn, B, 0, stream>>>(deg, bsum, n);
    k_scan_top<<<1, 512, 0, stream>>>(bsum, gn);
    k_row_start<<<gn, B, 0, stream>>>(deg, bsum, row_start, dinv, n);
    k_fat2<<<2 * gn4, B, 0, stream>>>(src, dst, row_start, rank, csr, dinv, (float4*)g1, n, E);
    k_gather1<<<gn4, B, 0, stream>>>((const float4*)g1, csr, row_start, deg, dinv, b1, W2,
                                     (float4*)g2p, n);
    k_gather2<<<gn4, B, 0, stream>>>((const float4*)g2p, csr, row_start, deg, dinv, b2, out, n);
}

// Round 6
// 204.560 us; speedup vs baseline: 1.2667x; 1.1437x over previous
//
#include <hip/hip_runtime.h>
#include <math.h>

// ---------------------------------------------------------------------------
// GCN 2-layer. CSR built with a two-level bucket partition (all atomics in
// LDS, all global writes short contiguous runs):
//   k1a:   per-block LDS histogram of dst>>9  -> hist[P1][NBK]
//   k_scan: offsets per (block,bucket) + bucket bases (1 block)
//   k1b:   FAT: [scatter packed (src<<9|local) into bucket-major staging]
//               || [h = x@W1 (unscaled) -> g1]
//   k2:    per-bucket: LDS count+scan -> deg/dinv/row_start, place edges into
//          contiguous csr segment via LDS tickets, scale g1 rows by dinv
//   gather1 (+relu/bias+W2), gather2 (+bias+log_softmax)   [unchanged]
// ---------------------------------------------------------------------------

#define BSH 9
#define BNODES 512          // nodes per bucket = 1<<BSH
#define P1 128              // pass-1 edge-slice blocks

// ---- k1a: count edges per bucket, per edge-slice block ----
__global__ void k1a_count(const int* __restrict__ dst, int* __restrict__ hist,
                          int NBK, int E) {
    __shared__ int lh[512];
    for (int i = threadIdx.x; i < NBK; i += 256) lh[i] = 0;
    __syncthreads();
    int slice = (E + P1 - 1) / P1;
    int e0 = blockIdx.x * slice, e1 = min(E, e0 + slice);
    for (int e = e0 + threadIdx.x; e < e1; e += 256)
        atomicAdd(&lh[dst[e] >> BSH], 1);
    __syncthreads();
    for (int i = threadIdx.x; i < NBK; i += 256)
        hist[blockIdx.x * NBK + i] = lh[i];
}

// ---- k_scan: colpre[b][k] = sum_{b'<b} hist[b'][k]; bucket_base = excl scan of totals
__global__ void k_scan(const int* __restrict__ hist, int* __restrict__ colpre,
                       int* __restrict__ bucket_base, int NBK) {
    __shared__ int s[256];
    int k = threadIdx.x;
    int acc = 0;
    if (k < NBK) {
        #pragma unroll 8
        for (int b = 0; b < P1; ++b) {
            int v = hist[b * NBK + k];
            colpre[b * NBK + k] = acc;
            acc += v;
        }
    }
    s[k] = (k < NBK) ? acc : 0;
    __syncthreads();
    for (int o = 1; o < 256; o <<= 1) {   // inclusive scan
        int add = (k >= o) ? s[k - o] : 0;
        __syncthreads();
        s[k] += add;
        __syncthreads();
    }
    if (k < NBK) {
        bucket_base[k] = s[k] - acc;      // exclusive
        if (k == NBK - 1) bucket_base[NBK] = s[k];
    }
}

// ---- k1b FAT: bucket-major scatter || gemm1 (unscaled) ----
__global__ void k1b_fat(const int* __restrict__ src, const int* __restrict__ dst,
                        const int* __restrict__ colpre, const int* __restrict__ bucket_base,
                        unsigned int* __restrict__ staging,
                        const float* __restrict__ x, const float* __restrict__ W1,
                        float4* __restrict__ g1v, int NBK, int n, int E) {
    __shared__ float4 sW4[512];  // 8 KB, aliased by the scatter branch
    int b = blockIdx.x;
    if (b < P1) {
        int* loff = (int*)sW4;           // [NBK] absolute run offsets
        int* lcur = ((int*)sW4) + 512;   // [NBK] run cursors
        for (int i = threadIdx.x; i < NBK; i += 256) {
            loff[i] = bucket_base[i] + colpre[b * NBK + i];
            lcur[i] = 0;
        }
        __syncthreads();
        int slice = (E + P1 - 1) / P1;
        int e0 = b * slice, e1 = min(E, e0 + slice);
        for (int e = e0 + threadIdx.x; e < e1; e += 256) {
            int d = dst[e], s = src[e];
            int k = d >> BSH;
            int t = atomicAdd(&lcur[k], 1);
            staging[loff[k] + t] = ((unsigned int)s << BSH) | (unsigned int)(d & (BNODES - 1));
        }
    } else {
        int tid = threadIdx.x;
        for (int i = tid; i < 512; i += 256) sW4[i] = ((const float4*)W1)[i];
        __syncthreads();
        int idx = (b - P1) * 256 + tid;
        int row = idx >> 2, c4 = idx & 3;
        if (row >= n) return;
        const float4* xr = (const float4*)(x + (size_t)row * 128);
        float4 acc = make_float4(0.f, 0.f, 0.f, 0.f);
        for (int q = 0; q < 32; ++q) {
            float4 xv = xr[q];
            #pragma unroll
            for (int j = 0; j < 4; ++j) {
                float s = (j == 0) ? xv.x : (j == 1) ? xv.y : (j == 2) ? xv.z : xv.w;
                float4 w = sW4[(q * 4 + j) * 4 + c4];
                acc.x += s * w.x; acc.y += s * w.y; acc.z += s * w.z; acc.w += s * w.w;
            }
        }
        g1v[(size_t)row * 4 + c4] = acc;  // unscaled; k2 applies dinv
    }
}

// ---- k2: per-bucket CSR build + node meta + g1 scaling ----
__global__ void k2_bucket(const unsigned int* __restrict__ staging,
                          const int* __restrict__ bucket_base,
                          int* __restrict__ csr, int* __restrict__ deg,
                          float* __restrict__ dinv, int* __restrict__ row_start,
                          float4* __restrict__ g1v, int n) {
    __shared__ int lh[512], lrow[512], lcur[512], part[256];
    __shared__ float ldv[512];
    int kb = blockIdx.x;
    int node0 = kb << BSH;
    int nloc = min(BNODES, n - node0);
    int ebase = bucket_base[kb], ecnt = bucket_base[kb + 1] - ebase;
    int t = threadIdx.x;
    lh[t] = 0; lh[t + 256] = 0; lcur[t] = 0; lcur[t + 256] = 0;
    __syncthreads();
    for (int e = t; e < ecnt; e += 256)
        atomicAdd(&lh[staging[ebase + e] & (BNODES - 1)], 1);
    __syncthreads();
    // exclusive scan lh[0..511] -> lrow
    int a = lh[2 * t], c = lh[2 * t + 1];
    part[t] = a + c;
    __syncthreads();
    for (int o = 1; o < 256; o <<= 1) {
        int add = (t >= o) ? part[t - o] : 0;
        __syncthreads();
        part[t] += add;
        __syncthreads();
    }
    int pre = (t == 0) ? 0 : part[t - 1];
    lrow[2 * t] = pre; lrow[2 * t + 1] = pre + a;
    __syncthreads();
    // node meta
    for (int i = t; i < nloc; i += 256) {
        int dgv = lh[i];
        deg[node0 + i] = dgv;
        row_start[node0 + i] = ebase + lrow[i];
        float dv = rsqrtf((float)(dgv + 1));  // +1 = self-loop
        dinv[node0 + i] = dv;
        ldv[i] = dv;
    }
    __syncthreads();
    // place edges into contiguous csr segment
    for (int e = t; e < ecnt; e += 256) {
        unsigned int p = staging[ebase + e];
        int loc = p & (BNODES - 1);
        int s = (int)(p >> BSH);
        int tk = atomicAdd(&lcur[loc], 1);
        csr[ebase + lrow[loc] + tk] = s;
    }
    // scale this bucket's g1 rows by dinv
    for (int j = t; j < nloc * 4; j += 256) {
        float dv = ldv[j >> 2];
        float4 v = g1v[(size_t)node0 * 4 + j];
        v.x *= dv; v.y *= dv; v.z *= dv; v.w *= dv;
        g1v[(size_t)node0 * 4 + j] = v;
    }
}

// ---- gathers (unchanged from R5) ----
__global__ void k_gather1(const float4* __restrict__ g1v, const int* __restrict__ csr,
                          const int* __restrict__ row_start, const int* __restrict__ deg,
                          const float* __restrict__ dinv, const float* __restrict__ b1,
                          const float* __restrict__ W2, float4* __restrict__ g2p, int n) {
    int idx = blockIdx.x * 256 + threadIdx.x;
    int i = idx >> 2, c4 = idx & 3;
    if (i >= n) return;
    int off = row_start[i], dg = deg[i];
    float4 acc = g1v[(size_t)i * 4 + c4];  // self-loop term
    for (int k = 0; k < dg; ++k) {
        int s = csr[off + k];
        float4 v = g1v[(size_t)s * 4 + c4];
        acc.x += v.x; acc.y += v.y; acc.z += v.z; acc.w += v.w;
    }
    float di = dinv[i];
    float z0 = fmaxf(0.f, di * acc.x + b1[c4 * 4 + 0]);
    float z1 = fmaxf(0.f, di * acc.y + b1[c4 * 4 + 1]);
    float z2 = fmaxf(0.f, di * acc.z + b1[c4 * 4 + 2]);
    float z3 = fmaxf(0.f, di * acc.w + b1[c4 * 4 + 3]);
    const float* w = W2 + c4 * 12;  // rows 4*c4 .. 4*c4+3 of [16][3]
    float o0 = z0 * w[0] + z1 * w[3] + z2 * w[6] + z3 * w[9];
    float o1 = z0 * w[1] + z1 * w[4] + z2 * w[7] + z3 * w[10];
    float o2 = z0 * w[2] + z1 * w[5] + z2 * w[8] + z3 * w[11];
    o0 += __shfl_xor(o0, 1); o0 += __shfl_xor(o0, 2);
    o1 += __shfl_xor(o1, 1); o1 += __shfl_xor(o1, 2);
    o2 += __shfl_xor(o2, 1); o2 += __shfl_xor(o2, 2);
    if (c4 == 0) g2p[i] = make_float4(di * o0, di * o1, di * o2, 0.f);
}

__global__ void k_gather2(const float4* __restrict__ g2p, const int* __restrict__ csr,
                          const int* __restrict__ row_start, const int* __restrict__ deg,
                          const float* __restrict__ dinv, const float* __restrict__ b2,
                          float* __restrict__ out, int n) {
    int idx = blockIdx.x * 256 + threadIdx.x;
    int i = idx >> 2, t = idx & 3;
    if (i >= n) return;
    int off = row_start[i], dg = deg[i];
    float v0 = 0.f, v1 = 0.f, v2 = 0.f;
    for (int k = t; k < dg; k += 4) {
        int s = csr[off + k];
        float4 g = g2p[s];
        v0 += g.x; v1 += g.y; v2 += g.z;
    }
    v0 += __shfl_xor(v0, 1); v0 += __shfl_xor(v0, 2);
    v1 += __shfl_xor(v1, 1); v1 += __shfl_xor(v1, 2);
    v2 += __shfl_xor(v2, 1); v2 += __shfl_xor(v2, 2);
    if (t != 0) return;
    float4 self = g2p[i];
    float di = dinv[i];
    float a0 = di * (v0 + self.x) + b2[0];
    float a1 = di * (v1 + self.y) + b2[1];
    float a2 = di * (v2 + self.z) + b2[2];
    float m = fmaxf(a0, fmaxf(a1, a2));
    float e0 = expf(a0 - m), e1 = expf(a1 - m), e2 = expf(a2 - m);
    float lse = logf(e0 + e1 + e2);
    out[(size_t)i * 3 + 0] = a0 - m - lse;
    out[(size_t)i * 3 + 1] = a1 - m - lse;
    out[(size_t)i * 3 + 2] = a2 - m - lse;
}

// ======================== launch ========================
extern "C" void kernel_launch(void* const* d_in, const int* in_sizes, int n_in,
                              void* d_out, int out_size, void* d_ws, size_t ws_size,
                              hipStream_t stream) {
    const float* x  = (const float*)d_in[0];
    const int*   ei = (const int*)d_in[1];      // [2][E]
    const float* W1 = (const float*)d_in[2];    // [128][16]
    const float* b1 = (const float*)d_in[3];    // [16]
    const float* W2 = (const float*)d_in[4];    // [16][3]
    const float* b2 = (const float*)d_in[5];    // [3]
    float* out = (float*)d_out;

    const int n = in_sizes[0] / 128;   // 100000
    const int E = in_sizes[1] / 2;     // 1600000
    const int* src = ei;
    const int* dst = ei + E;

    const int NBK = (n + BNODES - 1) >> BSH;  // 196 buckets

    // workspace layout, 256B-aligned chunks
    auto align = [](size_t v) { return (v + 255) & ~(size_t)255; };
    char* ws = (char*)d_ws;
    size_t o = 0;
    int* hist        = (int*)(ws + o); o = align(o + (size_t)P1 * NBK * 4);
    int* colpre      = (int*)(ws + o); o = align(o + (size_t)P1 * NBK * 4);
    int* bucket_base = (int*)(ws + o); o = align(o + (size_t)(NBK + 1) * 4);
    int* deg         = (int*)(ws + o); o = align(o + (size_t)n * 4);
    float* dinv      = (float*)(ws + o); o = align(o + (size_t)n * 4);
    int* row_start   = (int*)(ws + o); o = align(o + (size_t)n * 4);
    unsigned int* staging = (unsigned int*)(ws + o); o = align(o + (size_t)E * 4);
    int* csr         = (int*)(ws + o); o = align(o + (size_t)E * 4);
    float* g1        = (float*)(ws + o); o = align(o + (size_t)16 * n * 4);
    float* g2p       = (float*)(ws + o); o = align(o + (size_t)4 * n * 4);

    const int B = 256;
    int gn4 = (4 * n + B - 1) / B;     // 1563

    k1a_count<<<P1, B, 0, stream>>>(dst, hist, NBK, E);
    k_scan<<<1, 256, 0, stream>>>(hist, colpre, bucket_base, NBK);
    k1b_fat<<<P1 + gn4, B, 0, stream>>>(src, dst, colpre, bucket_base, staging,
                                        x, W1, (float4*)g1, NBK, n, E);
    k2_bucket<<<NBK, B, 0, stream>>>(staging, bucket_base, csr, deg, dinv, row_start,
                                     (float4*)g1, n);
    k_gather1<<<gn4, B, 0, stream>>>((const float4*)g1, csr, row_start, deg, dinv, b1, W2,
                                     (float4*)g2p, n);
    k_gather2<<<gn4, B, 0, stream>>>((const float4*)g2p, csr, row_start, deg, dinv, b2, out, n);
}